// Round 7
// baseline (263.974 us; speedup 1.0000x reference)
//
#include <hip/hip_runtime.h>
#include <math.h>

#define BB    4
#define CINN  32
#define COUTT 32
#define KCL   32
#define MM    16
#define AREA  9
#define SS    4096
#define FF    288
#define KMIT  10
#define NBPB  16     // blocks per batch
#define NB    (BB*NBPB)
#define TPB   256    // 1 thread = 1 point

typedef float    f32x4 __attribute__((ext_vector_type(4)));
typedef unsigned u32x4 __attribute__((ext_vector_type(4)));

// ---- coherent (cross-XCD) point ops: bypass L1+L2, served at coherent point ----
__device__ __forceinline__ void store_x4_coh(float* p, f32x4 v) {
    asm volatile("global_store_dwordx4 %0, %1, off sc0 sc1" :: "v"(p), "v"(v) : "memory");
}
__device__ __forceinline__ void store_dw_coh(float* p, float v) {
    asm volatile("global_store_dword %0, %1, off sc0 sc1" :: "v"(p), "v"(v) : "memory");
}
__device__ __forceinline__ void store_u32_coh(unsigned* p, unsigned v) {
    asm volatile("global_store_dword %0, %1, off sc0 sc1" :: "v"(p), "v"(v) : "memory");
}
__device__ __forceinline__ u32x4 load_u4_coh(const unsigned* p) {
    u32x4 r;
    asm volatile("global_load_dwordx4 %0, %1, off sc0 sc1\n\ts_waitcnt vmcnt(0)"
                 : "=v"(r) : "v"(p) : "memory");
    return r;
}
__device__ __forceinline__ f32x4 load_x4_coh(const float* p) {
    f32x4 r;
    asm volatile("global_load_dwordx4 %0, %1, off sc0 sc1" : "=v"(r) : "v"(p) : "memory");
    return r;
}
__device__ __forceinline__ float load_dw_coh(const float* p) {
    float r;
    asm volatile("global_load_dword %0, %1, off sc0 sc1" : "=v"(r) : "v"(p) : "memory");
    return r;
}

// exact-order distance for rows k2 and k2+1 (two independent chains, per-k order = c0..c31)
#define DIST2(RA, RB, KOFF)                                                     \
    {                                                                           \
        float dA = 0.f, dB = 0.f;                                               \
        _Pragma("unroll")                                                       \
        for (int q = 0; q < 8; ++q) {                                           \
            _Pragma("unroll")                                                   \
            for (int j = 0; j < 4; ++j) {                                       \
                float a = p4[q][j] - RA[q][j]; dA += a * a;                      \
                float bb = p4[q][j] - RB[q][j]; dB += bb * bb;                   \
            }                                                                   \
        }                                                                       \
        if (dA < dmin) { dmin = dA; kmin = (KOFF); }                            \
        if (dB < dmin) { dmin = dB; kmin = (KOFF) + 1; }                        \
    }

// ---------------- fused: feat + init + 10x Lloyd + final assign + MLP heads ----------------
__global__ __launch_bounds__(TPB) void kmeans_mlp_fused(
        const float* __restrict__ x,
        int* __restrict__ idx, float* __restrict__ psums, float* __restrict__ pcnts,
        unsigned* __restrict__ flags,
        const float* __restrict__ kh_w1, const float* __restrict__ kh_b1,
        const float* __restrict__ kh_w2, const float* __restrict__ kh_b2,
        const float* __restrict__ area_w, const float* __restrict__ area_b,
        const float* __restrict__ cin_w, const float* __restrict__ cin_b,
        const float* __restrict__ cout_w, const float* __restrict__ cout_b,
        const float* __restrict__ bh_w1, const float* __restrict__ bh_b1,
        const float* __restrict__ bh_w2, const float* __restrict__ bh_b2,
        const float* __restrict__ bh_w3, const float* __restrict__ bh_b3,
        float* __restrict__ wprod, float* __restrict__ wcoutA, float* __restrict__ biasA)
{
    __shared__ __align__(16) float cl[KCL * CINN];     // 4 KB centroids (block copy)
    __shared__ __align__(16) float pl[TPB * CINN];     // 32 KB point features
    __shared__ int   kms[TPB];                         // 1 KB assignments
    __shared__ float f1s[4][MM], g1s[4][MM], f2s[4][MM], g2s[4][MM];
    __shared__ float wcs[4][CINN], was[4][AREA];

    int blk = blockIdx.x;
    int b   = blk >> 4;
    int nbq = blk & 15;
    int tid = threadIdx.x;
    int lane = tid & 63;
    int s = (nbq << 8) + tid;
    int h = s >> 6, w = s & 63;
    const float* xb = x + ((size_t)(b * CINN) << 12);
    const int offA[9] = { -65, -64, -63, -1, 0, 1, 63, 64, 65 };

    // ---- feat of own point (3x3 box mean) into registers ----
    f32x4 p4[8];
    {
        const float* xc = xb + (h << 6) + w;
        bool vh0 = h > 0, vh2 = h < 63, vw0 = w > 0, vw2 = w < 63;
        bool va[9] = { vh0&&vw0, vh0, vh0&&vw2, vw0, true, vw2, vh2&&vw0, vh2, vh2&&vw2 };
        #pragma unroll
        for (int q = 0; q < 8; ++q) {
            #pragma unroll
            for (int j = 0; j < 4; ++j) {
                const float* xp = xc + ((size_t)(q * 4 + j) << 12);
                float sm = 0.f;
                #pragma unroll
                for (int a = 0; a < 9; ++a) sm += va[a] ? xp[offA[a]] : 0.f;
                p4[q][j] = sm * (1.f / 9.f);
            }
        }
    }
    // ---- write p to LDS once (rotated scalar writes -> conflict-free) ----
    #pragma unroll
    for (int j = 0; j < CINN; ++j) {
        int c = (tid + j) & 31;
        pl[tid * CINN + c] = p4[c >> 2][c & 3];
    }
    // ---- redundant init: every block computes the 32 linspace init centroids itself ----
    {
        int kinit = tid >> 3, cg = (tid & 7) << 2;
        int si = (kinit * 4095) / 31;
        int hi_ = si >> 6, wi_ = si & 63;
        bool vh0 = hi_ > 0, vh2 = hi_ < 63, vw0 = wi_ > 0, vw2 = wi_ < 63;
        bool va[9] = { vh0&&vw0, vh0, vh0&&vw2, vw0, true, vw2, vh2&&vw0, vh2, vh2&&vw2 };
        const float* xc = xb + (hi_ << 6) + wi_;
        #pragma unroll
        for (int j = 0; j < 4; ++j) {
            const float* xp = xc + ((size_t)(cg + j) << 12);
            float sm = 0.f;
            #pragma unroll
            for (int a = 0; a < 9; ++a) sm += va[a] ? xp[offA[a]] : 0.f;
            cl[kinit * CINN + cg + j] = sm * (1.f / 9.f);
        }
    }
    __syncthreads();

    int kq = tid >> 3, cq = tid & 7;
    const f32x4* cl4 = reinterpret_cast<const f32x4*>(cl);
    const f32x4* pl4 = reinterpret_cast<const f32x4*>(pl);
    unsigned* flagb = flags + b * 16;                 // one 64B line per batch
    int kmin = 0;

    for (int it = 0; it < KMIT; ++it) {
        // ---- assign: 2-k interleaved exact chains, rows preloaded to registers ----
        float dmin = 3.4e38f; kmin = 0;
        #pragma unroll 2
        for (int k2 = 0; k2 < KCL; k2 += 2) {
            f32x4 ra[8], rb[8];
            #pragma unroll
            for (int q = 0; q < 8; ++q) { ra[q] = cl4[k2 * 8 + q]; rb[q] = cl4[k2 * 8 + 8 + q]; }
            DIST2(ra, rb, k2);
        }
        kms[tid] = kmin;
        __syncthreads();
        // ---- single-pass one-hot segment-sum: thread owns (kq, c-quad), scans 256 points ----
        f32x4 av = {0.f, 0.f, 0.f, 0.f};
        float an = 0.f;
        {
            int   kmA = kms[0];
            f32x4 pvA = pl4[cq];
            for (int sp = 0; sp < 256; sp += 2) {
                int   kmB = kms[sp + 1];
                f32x4 pvB = pl4[(sp + 1) * 8 + cq];
                float m = (kmA == kq) ? 1.f : 0.f;
                av += m * pvA; an += m;
                if (sp + 2 < 256) { kmA = kms[sp + 2]; pvA = pl4[(sp + 2) * 8 + cq]; }
                float m2 = (kmB == kq) ? 1.f : 0.f;
                av += m2 * pvB; an += m2;
            }
        }
        // ---- coherent partial write (parity double-buffered), fully coalesced ----
        int par = it & 1;
        float* ps = psums + ((size_t)(par * NB) << 10);
        float* pc = pcnts + par * NB * KCL;
        store_x4_coh(ps + ((size_t)blk << 10) + (tid << 2), av);
        if (cq == 0) store_dw_coh(pc + blk * KCL + kq, an);
        asm volatile("s_waitcnt vmcnt(0)" ::: "memory");   // this wave's stores retired
        __syncthreads();                                   // => whole block's stores retired
        if (tid == 0) store_u32_coh(flagb + nbq, (unsigned)(it + 1));
        // ---- poll flag line until all 16 blocks of this batch posted it+1 ----
        if (tid == 0) {
            for (;;) {
                u32x4 f0 = load_u4_coh(flagb);
                u32x4 f1 = load_u4_coh(flagb + 4);
                u32x4 f2 = load_u4_coh(flagb + 8);
                u32x4 f3 = load_u4_coh(flagb + 12);
                unsigned mn = f0[0];
                #pragma unroll
                for (int j = 1; j < 4; ++j) mn = mn < f0[j] ? mn : f0[j];
                #pragma unroll
                for (int j = 0; j < 4; ++j) { mn = mn < f1[j] ? mn : f1[j];
                                              mn = mn < f2[j] ? mn : f2[j];
                                              mn = mn < f3[j] ? mn : f3[j]; }
                if (mn >= (unsigned)(it + 1)) break;
                __builtin_amdgcn_s_sleep(8);
            }
        }
        __syncthreads();
        // ---- redundant update: every block reduces the 16 partials in fixed order ----
        {
            f32x4 v[NBPB]; float cn[NBPB];
            #pragma unroll
            for (int q = 0; q < NBPB; ++q)
                v[q] = load_x4_coh(ps + ((size_t)((b << 4) + q) << 10) + (tid << 2));
            #pragma unroll
            for (int q = 0; q < NBPB; ++q)
                cn[q] = load_dw_coh(pc + ((b << 4) + q) * KCL + kq);
            asm volatile("s_waitcnt vmcnt(0)" ::: "memory");
            __builtin_amdgcn_sched_barrier(0);             // rule #18: no hoisting past the wait
            float sx = v[0][0], sy = v[0][1], sz = v[0][2], sw = v[0][3], ct = cn[0];
            #pragma unroll
            for (int q = 1; q < NBPB; ++q) {
                sx += v[q][0]; sy += v[q][1]; sz += v[q][2]; sw += v[q][3]; ct += cn[q];
            }
            float ctm = fmaxf(ct, 1.f);
            f32x4 old4 = cl4[kq * 8 + cq];
            f32x4 nc;
            nc[0] = (ct > 0.f) ? sx / ctm : old4[0];
            nc[1] = (ct > 0.f) ? sy / ctm : old4[1];
            nc[2] = (ct > 0.f) ? sz / ctm : old4[2];
            nc[3] = (ct > 0.f) ? sw / ctm : old4[3];
            __syncthreads();                               // all reads of old cl done
            *reinterpret_cast<f32x4*>(&cl[(kq * 8 + cq) * 4]) = nc;
        }
        __syncthreads();
    }

    // ---- final assign with c_10 ----
    {
        float dmin = 3.4e38f; kmin = 0;
        #pragma unroll 2
        for (int k2 = 0; k2 < KCL; k2 += 2) {
            f32x4 ra[8], rb[8];
            #pragma unroll
            for (int q = 0; q < 8; ++q) { ra[q] = cl4[k2 * 8 + q]; rb[q] = cl4[k2 * 8 + 8 + q]; }
            DIST2(ra, rb, k2);
        }
        idx[(size_t)b * SS + s] = kmin;
    }

    // ---- MLP heads on the nbq==0 block of each batch (has final centroids in cl) ----
    if (nbq == 0) {
        int k2 = tid >> 6;                     // 4 clusters in parallel, 64 lanes each
        for (int kk = 0; kk < 8; ++kk) {
            int k = kk * 4 + k2;
            const float* cc = &cl[k * CINN];
            if (lane < MM) {
                float a = kh_b1[lane], a2 = bh_b1[lane];
                for (int c = 0; c < CINN; ++c) {
                    float cv = cc[c];
                    a  += cv * kh_w1[c * MM + lane];
                    a2 += cv * bh_w1[c * MM + lane];
                }
                f1s[k2][lane] = fmaxf(a, 0.f); g1s[k2][lane] = fmaxf(a2, 0.f);
            }
            __syncthreads();
            if (lane < MM) {
                float a = kh_b2[lane], a2 = bh_b2[lane];
                for (int m = 0; m < MM; ++m) {
                    a  += f1s[k2][m] * kh_w2[m * MM + lane];
                    a2 += g1s[k2][m] * bh_w2[m * MM + lane];
                }
                f2s[k2][lane] = fmaxf(a, 0.f); g2s[k2][lane] = fmaxf(a2, 0.f);
            }
            __syncthreads();
            int bk = b * KCL + k;
            if (lane < CINN) {
                float ac = cin_b[lane], ao = cout_b[lane], ab = bh_b3[lane];
                for (int m = 0; m < MM; ++m) {
                    float f2v = f2s[k2][m];
                    ac += f2v * cin_w[m * CINN + lane];
                    ao += f2v * cout_w[m * COUTT + lane];
                    ab += g2s[k2][m] * bh_w3[m * COUTT + lane];
                }
                wcs[k2][lane] = 1.f / (1.f + expf(-ac));
                wcoutA[(size_t)bk * COUTT + lane] = 1.f / (1.f + expf(-ao));
                biasA[(size_t)bk * COUTT + lane] = ab;
            } else if (lane < CINN + AREA) {
                int a9 = lane - CINN;
                float aa = area_b[a9];
                for (int m = 0; m < MM; ++m) aa += f2s[k2][m] * area_w[m * AREA + a9];
                was[k2][a9] = 1.f / (1.f + expf(-aa));
            }
            __syncthreads();
            for (int f = lane; f < FF; f += 64)
                wprod[(size_t)bk * FF + f] = wcs[k2][f / 9] * was[k2][f % 9];
        }
    }
}

// ---------------- main factorized conv ----------------
__global__ __launch_bounds__(256) void conv_kernel(
        const float* __restrict__ x, const int* __restrict__ idx,
        const float* __restrict__ wprod, const float* __restrict__ wcoutA,
        const float* __restrict__ biasA, const float* __restrict__ base,
        float* __restrict__ out) {
    __shared__ __align__(16) float bl[FF * COUTT];     // 36.9 KB
    int blk = blockIdx.x;                  // B*128
    int b = blk >> 7;
    int s0 = (blk & 127) << 5;             // 32 points per block
    int tid = threadIdx.x;
    for (int i = tid; i < FF * COUTT; i += 256) bl[i] = base[i];
    __syncthreads();
    int co4 = (tid & 7) << 2;              // 4 consecutive cout per thread
    int s = s0 + (tid >> 3);
    int h = s >> 6, w = s & 63;
    int k = idx[(size_t)b * SS + s];
    const float* wp = wprod + ((size_t)b * KCL + k) * FF;
    const float* xb = x + ((size_t)(b * CINN) << 12) + (h << 6) + w;
    bool vh0 = h > 0, vh2 = h < 63, vw0 = w > 0, vw2 = w < 63;
    bool va[9] = { vh0 && vw0, vh0, vh0 && vw2,
                   vw0,        true, vw2,
                   vh2 && vw0, vh2, vh2 && vw2 };
    const int offA[9] = { -65, -64, -63, -1, 0, 1, 63, 64, 65 };
    float ax = 0.f, ay = 0.f, az = 0.f, aw = 0.f;
    int f = 0;
    for (int c = 0; c < CINN; ++c) {
        const float* xp = xb + (c << 12);
        #pragma unroll
        for (int a = 0; a < 9; ++a) {
            float val = va[a] ? xp[offA[a]] : 0.f;
            float q = val * wp[f];
            float4 bb = *reinterpret_cast<const float4*>(&bl[(f << 5) + co4]);
            ax += q * bb.x; ay += q * bb.y; az += q * bb.z; aw += q * bb.w;
            ++f;
        }
    }
    const float* wo = wcoutA + ((size_t)b * KCL + k) * COUTT + co4;
    const float* bo = biasA + ((size_t)b * KCL + k) * COUTT + co4;
    float* op = out + ((size_t)(b * COUTT + co4) << 12) + s;
    op[0]     = wo[0] * ax + bo[0];
    op[4096]  = wo[1] * ay + bo[1];
    op[8192]  = wo[2] * az + bo[2];
    op[12288] = wo[3] * aw + bo[3];
}

extern "C" void kernel_launch(void* const* d_in, const int* in_sizes, int n_in,
                              void* d_out, int out_size, void* d_ws, size_t ws_size,
                              hipStream_t stream) {
    (void)in_sizes; (void)n_in; (void)out_size; (void)ws_size;
    const float* x      = (const float*)d_in[0];
    const float* kh_w1  = (const float*)d_in[1];
    const float* kh_b1  = (const float*)d_in[2];
    const float* kh_w2  = (const float*)d_in[3];
    const float* kh_b2  = (const float*)d_in[4];
    const float* area_w = (const float*)d_in[5];
    const float* area_b = (const float*)d_in[6];
    const float* cin_w  = (const float*)d_in[7];
    const float* cin_b  = (const float*)d_in[8];
    const float* cout_w = (const float*)d_in[9];
    const float* cout_b = (const float*)d_in[10];
    const float* base   = (const float*)d_in[11];
    const float* bh_w1  = (const float*)d_in[12];
    const float* bh_b1  = (const float*)d_in[13];
    const float* bh_w2  = (const float*)d_in[14];
    const float* bh_b2  = (const float*)d_in[15];
    const float* bh_w3  = (const float*)d_in[16];
    const float* bh_b3  = (const float*)d_in[17];
    float* out = (float*)d_out;

    unsigned* flags = (unsigned*)d_ws;                     // BB lines of 64B
    float* psums = (float*)d_ws + 16 * BB;                 // 2*NB*1024 = 524288 B
    float* pcnts = psums + (size_t)2 * NB * 1024;          // 2*NB*32
    int*   idx   = (int*)(pcnts + 2 * NB * KCL);           // B*S
    float* wprod = (float*)(idx + BB * SS);                // B*K*F
    float* wco   = wprod + (size_t)BB * KCL * FF;          // B*K*COUT
    float* bia   = wco + BB * KCL * COUTT;                 // B*K*COUT

    (void)hipMemsetAsync(flags, 0, 16 * BB * sizeof(unsigned), stream);
    kmeans_mlp_fused<<<NB, TPB, 0, stream>>>(x, idx, psums, pcnts, flags,
                                             kh_w1, kh_b1, kh_w2, kh_b2,
                                             area_w, area_b, cin_w, cin_b, cout_w, cout_b,
                                             bh_w1, bh_b1, bh_w2, bh_b2, bh_w3, bh_b3,
                                             wprod, wco, bia);
    conv_kernel<<<BB * 128, 256, 0, stream>>>(x, idx, wprod, wco, bia, base, out);
}

// Round 8
// 235.348 us; speedup vs baseline: 1.1216x; 1.1216x over previous
//
#include <hip/hip_runtime.h>
#include <math.h>

#define BB    4
#define CINN  32
#define COUTT 32
#define KCL   32
#define MM    16
#define AREA  9
#define SS    4096
#define FF    288
#define KMIT  10
#define NBPB  16     // blocks per batch
#define NB    (BB*NBPB)
#define TPB   256    // 1 thread = 1 point

typedef float f32x4 __attribute__((ext_vector_type(4)));
typedef float f32x2 __attribute__((ext_vector_type(2)));

// ---- coherent (cross-XCD) point ops: bypass L1+L2, served at coherent point ----
__device__ __forceinline__ void store_x4_coh(float* p, f32x4 v) {
    asm volatile("global_store_dwordx4 %0, %1, off sc0 sc1" :: "v"(p), "v"(v) : "memory");
}
__device__ __forceinline__ void store_dw_coh(float* p, float v) {
    asm volatile("global_store_dword %0, %1, off sc0 sc1" :: "v"(p), "v"(v) : "memory");
}
__device__ __forceinline__ f32x4 load_x4_coh(const float* p) {
    f32x4 r;
    asm volatile("global_load_dwordx4 %0, %1, off sc0 sc1" : "=v"(r) : "v"(p) : "memory");
    return r;
}
__device__ __forceinline__ float load_dw_coh(const float* p) {
    float r;
    asm volatile("global_load_dword %0, %1, off sc0 sc1" : "=v"(r) : "v"(p) : "memory");
    return r;
}

// exact-order distance for rows k2 and k2+1 (two independent chains, per-k order = c0..c31)
#define DIST2(RA, RB, KOFF)                                                     \
    {                                                                           \
        float dA = 0.f, dB = 0.f;                                               \
        _Pragma("unroll")                                                       \
        for (int q = 0; q < 8; ++q) {                                           \
            _Pragma("unroll")                                                   \
            for (int j = 0; j < 4; ++j) {                                       \
                float a = p4[q][j] - RA[q][j]; dA += a * a;                      \
                float bb = p4[q][j] - RB[q][j]; dB += bb * bb;                   \
            }                                                                   \
        }                                                                       \
        if (dA < dmin) { dmin = dA; kmin = (KOFF); }                            \
        if (dB < dmin) { dmin = dB; kmin = (KOFF) + 1; }                        \
    }

// ---------------- fused: feat + init + 10x Lloyd + final assign + MLP heads ----------------
__global__ __launch_bounds__(TPB, 1) void kmeans_mlp_fused(
        const float* __restrict__ x,
        int* __restrict__ idx, float* __restrict__ psums, float* __restrict__ pcnts,
        float* __restrict__ centW,
        const float* __restrict__ kh_w1, const float* __restrict__ kh_b1,
        const float* __restrict__ kh_w2, const float* __restrict__ kh_b2,
        const float* __restrict__ area_w, const float* __restrict__ area_b,
        const float* __restrict__ cin_w, const float* __restrict__ cin_b,
        const float* __restrict__ cout_w, const float* __restrict__ cout_b,
        const float* __restrict__ bh_w1, const float* __restrict__ bh_b1,
        const float* __restrict__ bh_w2, const float* __restrict__ bh_b2,
        const float* __restrict__ bh_w3, const float* __restrict__ bh_b3,
        float* __restrict__ wprod, float* __restrict__ wcoutA, float* __restrict__ biasA)
{
    __shared__ __align__(16) float pl[TPB * CINN];     // 32 KB point features
    __shared__ int   kms[TPB];                         // 1 KB assignments
    __shared__ float wsums[4][KCL * 34];               // 17.4 KB wave partials (stride 34)
    __shared__ float wcnt[4][KCL];
    __shared__ float f1s[4][MM], g1s[4][MM], f2s[4][MM], g2s[4][MM];
    __shared__ float wcs[4][CINN], was[4][AREA];

    int blk = blockIdx.x;
    int b   = blk >> 4;
    int nbq = blk & 15;
    int tid = threadIdx.x;
    int lane = tid & 63, wid = tid >> 6;
    int s = (nbq << 8) + tid;
    int h = s >> 6, w = s & 63;
    const float* xb = x + ((size_t)(b * CINN) << 12);
    float* centB = centW + ((size_t)blk << 10);        // block-private centroids (cached)
    const int offA[9] = { -65, -64, -63, -1, 0, 1, 63, 64, 65 };

    // ---- feat of own point (3x3 box mean) into registers ----
    f32x4 p4[8];
    {
        const float* xc = xb + (h << 6) + w;
        bool vh0 = h > 0, vh2 = h < 63, vw0 = w > 0, vw2 = w < 63;
        bool va[9] = { vh0&&vw0, vh0, vh0&&vw2, vw0, true, vw2, vh2&&vw0, vh2, vh2&&vw2 };
        #pragma unroll
        for (int q = 0; q < 8; ++q) {
            #pragma unroll
            for (int j = 0; j < 4; ++j) {
                const float* xp = xc + ((size_t)(q * 4 + j) << 12);
                float sm = 0.f;
                #pragma unroll
                for (int a = 0; a < 9; ++a) sm += va[a] ? xp[offA[a]] : 0.f;
                p4[q][j] = sm * (1.f / 9.f);
            }
        }
    }
    // ---- write p to LDS once (rotated scalar writes -> conflict-free) ----
    #pragma unroll
    for (int j = 0; j < CINN; ++j) {
        int c = (tid + j) & 31;
        pl[tid * CINN + c] = p4[c >> 2][c & 3];
    }
    // ---- redundant init: every block computes the 32 linspace init centroids into centB ----
    {
        int kinit = tid >> 3, cg = (tid & 7) << 2;
        int si = (kinit * 4095) / 31;
        int hi_ = si >> 6, wi_ = si & 63;
        bool vh0 = hi_ > 0, vh2 = hi_ < 63, vw0 = wi_ > 0, vw2 = wi_ < 63;
        bool va[9] = { vh0&&vw0, vh0, vh0&&vw2, vw0, true, vw2, vh2&&vw0, vh2, vh2&&vw2 };
        const float* xc = xb + (hi_ << 6) + wi_;
        f32x4 iv;
        #pragma unroll
        for (int j = 0; j < 4; ++j) {
            const float* xp = xc + ((size_t)(cg + j) << 12);
            float sm = 0.f;
            #pragma unroll
            for (int a = 0; a < 9; ++a) sm += va[a] ? xp[offA[a]] : 0.f;
            iv[j] = sm * (1.f / 9.f);
        }
        *reinterpret_cast<f32x4*>(centB + kinit * CINN + cg) = iv;
    }
    __syncthreads();

    int kq = tid >> 3, cq = tid & 7;                 // combine/update slot: (k, c-quad)
    int kb = (lane >> 3) << 2, cq8 = lane & 7;       // scan slot: 4 k's, one c-quad
    const f32x4* pl4 = reinterpret_cast<const f32x4*>(pl);
    int kmin = 0;

    for (int it = 0; it < KMIT; ++it) {
        // ---- assign: centroid rows via all-lane-broadcast cached global loads ----
        const f32x4* cB4 = reinterpret_cast<const f32x4*>(centB);
        float dmin = 3.4e38f; kmin = 0;
        #pragma unroll 2
        for (int k2 = 0; k2 < KCL; k2 += 2) {
            f32x4 ra[8], rb[8];
            #pragma unroll
            for (int q = 0; q < 8; ++q) { ra[q] = cB4[k2 * 8 + q]; rb[q] = cB4[k2 * 8 + 8 + q]; }
            DIST2(ra, rb, k2);
        }
        kms[tid] = kmin;
        __syncthreads();
        // ---- wave-split one-hot scan: wave sums its OWN 64 points (fixed order) ----
        {
            f32x4 av0 = 0.f, av1 = 0.f, av2 = 0.f, av3 = 0.f, an4 = 0.f;
            int sbase = wid << 6;
            for (int i = 0; i < 64; ++i) {
                int sp = sbase + i;
                int km = kms[sp];                                     // broadcast b32
                f32x4 pv = pl4[sp * 8 + cq8];                         // 8-way-bcast b128
                float m0 = (km == kb + 0) ? 1.f : 0.f;
                float m1 = (km == kb + 1) ? 1.f : 0.f;
                float m2 = (km == kb + 2) ? 1.f : 0.f;
                float m3 = (km == kb + 3) ? 1.f : 0.f;
                av0 += m0 * pv; av1 += m1 * pv; av2 += m2 * pv; av3 += m3 * pv;
                an4[0] += m0; an4[1] += m1; an4[2] += m2; an4[3] += m3;
            }
            #pragma unroll
            for (int cc = 0; cc < 4; ++cc) {
                wsums[wid][(kb + 0) * 34 + cq8 * 4 + cc] = av0[cc];
                wsums[wid][(kb + 1) * 34 + cq8 * 4 + cc] = av1[cc];
                wsums[wid][(kb + 2) * 34 + cq8 * 4 + cc] = av2[cc];
                wsums[wid][(kb + 3) * 34 + cq8 * 4 + cc] = av3[cc];
            }
            if (cq8 == 0) {
                wcnt[wid][kb + 0] = an4[0]; wcnt[wid][kb + 1] = an4[1];
                wcnt[wid][kb + 2] = an4[2]; wcnt[wid][kb + 3] = an4[3];
            }
        }
        __syncthreads();
        // ---- combine 4 wave partials, coherent psums store (parity double-buffered) ----
        int par = it & 1;
        float* ps = psums + ((size_t)(par * NB) << 10);
        float* pc = pcnts + par * NB * KCL;
        {
            f32x2 lo = {0.f, 0.f}, hi = {0.f, 0.f};
            #pragma unroll
            for (int ww = 0; ww < 4; ++ww) {
                lo += *reinterpret_cast<const f32x2*>(&wsums[ww][kq * 34 + cq * 4]);
                hi += *reinterpret_cast<const f32x2*>(&wsums[ww][kq * 34 + cq * 4 + 2]);
            }
            f32x4 v = { lo[0], lo[1], hi[0], hi[1] };
            store_x4_coh(ps + ((size_t)blk << 10) + (tid << 2), v);
        }
        asm volatile("s_waitcnt vmcnt(0)" ::: "memory");   // psums retired at coherent point
        __syncthreads();                                   // whole block's psums retired
        float thr = (float)((it + 1) << 9);                // count sentinel bias
        if (cq == 0) {
            float cnt = wcnt[0][kq] + wcnt[1][kq] + wcnt[2][kq] + wcnt[3][kq];
            store_dw_coh(pc + blk * KCL + kq, thr + cnt);  // count doubles as arrival flag
        }
        // ---- poll own 16 counts (one round-trip per retry) ----
        float cn[16];
        for (;;) {
            #pragma unroll
            for (int q = 0; q < 16; ++q)
                cn[q] = load_dw_coh(pc + ((b << 4) + q) * KCL + kq);
            asm volatile("s_waitcnt vmcnt(0)" ::: "memory");
            __builtin_amdgcn_sched_barrier(0);             // rule #18
            float mn = cn[0];
            #pragma unroll
            for (int q = 1; q < 16; ++q) mn = fminf(mn, cn[q]);
            if (mn >= thr) break;
            __builtin_amdgcn_s_sleep(4);
        }
        // ---- redundant update: fixed-order reduction of 16 partials ----
        {
            f32x4 v[16];
            #pragma unroll
            for (int q = 0; q < 16; ++q)
                v[q] = load_x4_coh(ps + ((size_t)((b << 4) + q) << 10) + (tid << 2));
            asm volatile("s_waitcnt vmcnt(0)" ::: "memory");
            __builtin_amdgcn_sched_barrier(0);             // rule #18
            float sx = v[0][0], sy = v[0][1], sz = v[0][2], sw = v[0][3];
            float ct = cn[0] - thr;
            #pragma unroll
            for (int q = 1; q < 16; ++q) {
                sx += v[q][0]; sy += v[q][1]; sz += v[q][2]; sw += v[q][3];
                ct += cn[q] - thr;
            }
            float ctm = fmaxf(ct, 1.f);
            f32x4 old4 = *reinterpret_cast<const f32x4*>(centB + kq * CINN + cq * 4);
            f32x4 nc;
            nc[0] = (ct > 0.f) ? sx / ctm : old4[0];
            nc[1] = (ct > 0.f) ? sy / ctm : old4[1];
            nc[2] = (ct > 0.f) ? sz / ctm : old4[2];
            nc[3] = (ct > 0.f) ? sw / ctm : old4[3];
            *reinterpret_cast<f32x4*>(centB + kq * CINN + cq * 4) = nc;  // own quad only
        }
        __syncthreads();   // centB fully written before next assign reads it
    }

    // ---- final assign with c_10 ----
    {
        const f32x4* cB4 = reinterpret_cast<const f32x4*>(centB);
        float dmin = 3.4e38f; kmin = 0;
        #pragma unroll 2
        for (int k2 = 0; k2 < KCL; k2 += 2) {
            f32x4 ra[8], rb[8];
            #pragma unroll
            for (int q = 0; q < 8; ++q) { ra[q] = cB4[k2 * 8 + q]; rb[q] = cB4[k2 * 8 + 8 + q]; }
            DIST2(ra, rb, k2);
        }
        idx[(size_t)b * SS + s] = kmin;
    }

    // ---- MLP heads on the nbq==0 block of each batch (centB holds final centroids) ----
    if (nbq == 0) {
        int k2 = tid >> 6;                     // 4 clusters in parallel, 64 lanes each
        for (int kk = 0; kk < 8; ++kk) {
            int k = kk * 4 + k2;
            const float* cc = centB + k * CINN;
            if (lane < MM) {
                float a = kh_b1[lane], a2 = bh_b1[lane];
                for (int c = 0; c < CINN; ++c) {
                    float cv = cc[c];
                    a  += cv * kh_w1[c * MM + lane];
                    a2 += cv * bh_w1[c * MM + lane];
                }
                f1s[k2][lane] = fmaxf(a, 0.f); g1s[k2][lane] = fmaxf(a2, 0.f);
            }
            __syncthreads();
            if (lane < MM) {
                float a = kh_b2[lane], a2 = bh_b2[lane];
                for (int m = 0; m < MM; ++m) {
                    a  += f1s[k2][m] * kh_w2[m * MM + lane];
                    a2 += g1s[k2][m] * bh_w2[m * MM + lane];
                }
                f2s[k2][lane] = fmaxf(a, 0.f); g2s[k2][lane] = fmaxf(a2, 0.f);
            }
            __syncthreads();
            int bk = b * KCL + k;
            if (lane < CINN) {
                float ac = cin_b[lane], ao = cout_b[lane], ab = bh_b3[lane];
                for (int m = 0; m < MM; ++m) {
                    float f2v = f2s[k2][m];
                    ac += f2v * cin_w[m * CINN + lane];
                    ao += f2v * cout_w[m * COUTT + lane];
                    ab += g2s[k2][m] * bh_w3[m * COUTT + lane];
                }
                wcs[k2][lane] = 1.f / (1.f + expf(-ac));
                wcoutA[(size_t)bk * COUTT + lane] = 1.f / (1.f + expf(-ao));
                biasA[(size_t)bk * COUTT + lane] = ab;
            } else if (lane < CINN + AREA) {
                int a9 = lane - CINN;
                float aa = area_b[a9];
                for (int m = 0; m < MM; ++m) aa += f2s[k2][m] * area_w[m * AREA + a9];
                was[k2][a9] = 1.f / (1.f + expf(-aa));
            }
            __syncthreads();
            for (int f = lane; f < FF; f += 64)
                wprod[(size_t)bk * FF + f] = wcs[k2][f / 9] * was[k2][f % 9];
        }
    }
}

// ---------------- main factorized conv ----------------
__global__ __launch_bounds__(256) void conv_kernel(
        const float* __restrict__ x, const int* __restrict__ idx,
        const float* __restrict__ wprod, const float* __restrict__ wcoutA,
        const float* __restrict__ biasA, const float* __restrict__ base,
        float* __restrict__ out) {
    __shared__ __align__(16) float bl[FF * COUTT];     // 36.9 KB
    int blk = blockIdx.x;                  // B*128
    int b = blk >> 7;
    int s0 = (blk & 127) << 5;             // 32 points per block
    int tid = threadIdx.x;
    for (int i = tid; i < FF * COUTT; i += 256) bl[i] = base[i];
    __syncthreads();
    int co4 = (tid & 7) << 2;              // 4 consecutive cout per thread
    int s = s0 + (tid >> 3);
    int h = s >> 6, w = s & 63;
    int k = idx[(size_t)b * SS + s];
    const float* wp = wprod + ((size_t)b * KCL + k) * FF;
    const float* xb = x + ((size_t)(b * CINN) << 12) + (h << 6) + w;
    bool vh0 = h > 0, vh2 = h < 63, vw0 = w > 0, vw2 = w < 63;
    bool va[9] = { vh0 && vw0, vh0, vh0 && vw2,
                   vw0,        true, vw2,
                   vh2 && vw0, vh2, vh2 && vw2 };
    const int offA[9] = { -65, -64, -63, -1, 0, 1, 63, 64, 65 };
    float ax = 0.f, ay = 0.f, az = 0.f, aw = 0.f;
    int f = 0;
    for (int c = 0; c < CINN; ++c) {
        const float* xp = xb + (c << 12);
        #pragma unroll
        for (int a = 0; a < 9; ++a) {
            float val = va[a] ? xp[offA[a]] : 0.f;
            float q = val * wp[f];
            float4 bb = *reinterpret_cast<const float4*>(&bl[(f << 5) + co4]);
            ax += q * bb.x; ay += q * bb.y; az += q * bb.z; aw += q * bb.w;
            ++f;
        }
    }
    const float* wo = wcoutA + ((size_t)b * KCL + k) * COUTT + co4;
    const float* bo = biasA + ((size_t)b * KCL + k) * COUTT + co4;
    float* op = out + ((size_t)(b * COUTT + co4) << 12) + s;
    op[0]     = wo[0] * ax + bo[0];
    op[4096]  = wo[1] * ay + bo[1];
    op[8192]  = wo[2] * az + bo[2];
    op[12288] = wo[3] * aw + bo[3];
}

extern "C" void kernel_launch(void* const* d_in, const int* in_sizes, int n_in,
                              void* d_out, int out_size, void* d_ws, size_t ws_size,
                              hipStream_t stream) {
    (void)in_sizes; (void)n_in; (void)out_size; (void)ws_size;
    const float* x      = (const float*)d_in[0];
    const float* kh_w1  = (const float*)d_in[1];
    const float* kh_b1  = (const float*)d_in[2];
    const float* kh_w2  = (const float*)d_in[3];
    const float* kh_b2  = (const float*)d_in[4];
    const float* area_w = (const float*)d_in[5];
    const float* area_b = (const float*)d_in[6];
    const float* cin_w  = (const float*)d_in[7];
    const float* cin_b  = (const float*)d_in[8];
    const float* cout_w = (const float*)d_in[9];
    const float* cout_b = (const float*)d_in[10];
    const float* base   = (const float*)d_in[11];
    const float* bh_w1  = (const float*)d_in[12];
    const float* bh_b1  = (const float*)d_in[13];
    const float* bh_w2  = (const float*)d_in[14];
    const float* bh_b2  = (const float*)d_in[15];
    const float* bh_w3  = (const float*)d_in[16];
    const float* bh_b3  = (const float*)d_in[17];
    float* out = (float*)d_out;

    float* pcnts = (float*)d_ws;                           // 2*NB*32  (memset 0 each launch)
    float* psums = pcnts + 2 * NB * KCL;                   // 2*NB*1024
    float* centW = psums + (size_t)2 * NB * 1024;          // NB*1024 block-private centroids
    int*   idx   = (int*)(centW + (size_t)NB * 1024);      // B*S
    float* wprod = (float*)(idx + BB * SS);                // B*K*F
    float* wco   = wprod + (size_t)BB * KCL * FF;          // B*K*COUT
    float* bia   = wco + BB * KCL * COUTT;                 // B*K*COUT

    (void)hipMemsetAsync(pcnts, 0, 2 * NB * KCL * sizeof(float), stream);
    kmeans_mlp_fused<<<NB, TPB, 0, stream>>>(x, idx, psums, pcnts, centW,
                                             kh_w1, kh_b1, kh_w2, kh_b2,
                                             area_w, area_b, cin_w, cin_b, cout_w, cout_b,
                                             bh_w1, bh_b1, bh_w2, bh_b2, bh_w3, bh_b3,
                                             wprod, wco, bia);
    conv_kernel<<<BB * 128, 256, 0, stream>>>(x, idx, wprod, wco, bia, base, out);
}